// Round 15
// baseline (202.867 us; speedup 1.0000x reference)
//
#include <hip/hip_runtime.h>
#include <stdint.h>

// QuantizedLinear (BitNet ternary): out = x @ q^T + bias
// INT8 path (R13 numerics, absmax 3.06): ternary weights in i8; x per-row i8.
// R15 = R14 with the staging off-by-one fixed (tiles 2..63 need staging at
// t=0..61; R14's `t<61` left tile 63 unstaged -> absmax 56). Schedule:
// m201-faithful 2-phase/tile, 3 LDS buffers (96 KiB), counted VMW4 boundary
// publishes (never vmcnt(0) mid-loop), per-wave lgkmcnt(0) stagger, setprio,
// bijective XCD col-chunk swizzle.

#define M_DIM 8192
#define N_DIM 4096
#define K_DIM 4096
#define BM 256
#define BN 256
#define BK 64

typedef __attribute__((ext_vector_type(4))) int vi4;

#define BAR() asm volatile("s_barrier" ::: "memory")
#define VMW4() asm volatile("s_waitcnt vmcnt(4)" ::: "memory")
#define VMW0() asm volatile("s_waitcnt vmcnt(0)" ::: "memory")
#define SB0() __builtin_amdgcn_sched_barrier(0)
#define LGKM0()                                             \
  do {                                                      \
    SB0();                                                  \
    asm volatile("s_waitcnt lgkmcnt(0)" ::: "memory");      \
    SB0();                                                  \
  } while (0)

__device__ __forceinline__ void load_lds16(const void* g, void* l) {
  __builtin_amdgcn_global_load_lds(
      (const __attribute__((address_space(1))) void*)g,
      (__attribute__((address_space(3))) void*)l,
      16, 0, 0);
}

// ---------- K1: per-block partial sums of |w| (deterministic) ----------
__global__ __launch_bounds__(256) void k_abs_partial(const float* __restrict__ w,
                                                     double* __restrict__ partial) {
  const int tid = threadIdx.x;
  const size_t base = (size_t)blockIdx.x * 8192 + (size_t)tid * 4;
  double s = 0.0;
#pragma unroll
  for (int it = 0; it < 8; ++it) {
    const float4 v = *reinterpret_cast<const float4*>(w + base + (size_t)it * 1024);
    s += (double)fabsf(v.x) + (double)fabsf(v.y) + (double)fabsf(v.z) + (double)fabsf(v.w);
  }
  __shared__ double sd[256];
  sd[tid] = s;
  __syncthreads();
  for (int off = 128; off > 0; off >>= 1) {
    if (tid < off) sd[tid] += sd[tid + off];
    __syncthreads();
  }
  if (tid == 0) partial[blockIdx.x] = sd[0];
}

// ---------- K2: finalize gamma (fp32 like numpy) ----------
__global__ __launch_bounds__(256) void k_abs_final(const double* __restrict__ partial,
                                                   float* __restrict__ gamma_out) {
  const int tid = threadIdx.x;
  double s = 0.0;
  for (int i = tid; i < 2048; i += 256) s += partial[i];
  __shared__ double sd[256];
  sd[tid] = s;
  __syncthreads();
  for (int off = 128; off > 0; off >>= 1) {
    if (tid < off) sd[tid] += sd[tid + off];
    __syncthreads();
  }
  if (tid == 0) {
    float g = (float)(sd[0] / 16777216.0);  // mean over 4096*4096
    gamma_out[0] = g + 1e-5f;
  }
}

// ---------- K3: quantize W -> ternary int8 ----------
__global__ __launch_bounds__(256) void k_quant(const float* __restrict__ w,
                                               const float* __restrict__ gamma_p,
                                               int* __restrict__ qb) {
  const float g = gamma_p[0];
  const size_t n4 = (size_t)N_DIM * K_DIM / 4;
  const size_t stride = (size_t)gridDim.x * blockDim.x;
  for (size_t i = (size_t)blockIdx.x * blockDim.x + threadIdx.x; i < n4; i += stride) {
    const float4 v = reinterpret_cast<const float4*>(w)[i];
    float r;
    int a, b, c, d;
    r = rintf(v.x / g); a = (r >= 1.0f) ? 1 : ((r <= -1.0f) ? -1 : 0);
    r = rintf(v.y / g); b = (r >= 1.0f) ? 1 : ((r <= -1.0f) ? -1 : 0);
    r = rintf(v.z / g); c = (r >= 1.0f) ? 1 : ((r <= -1.0f) ? -1 : 0);
    r = rintf(v.w / g); d = (r >= 1.0f) ? 1 : ((r <= -1.0f) ? -1 : 0);
    qb[i] = (a & 0xff) | ((b & 0xff) << 8) | ((c & 0xff) << 16) | ((d & 0xff) << 24);
  }
}

// ---------- K4: x fp32 -> per-row-scaled int8 ----------
__global__ __launch_bounds__(256) void k_quant_x(const float* __restrict__ x,
                                                 signed char* __restrict__ xq,
                                                 float* __restrict__ xs) {
  const int row = blockIdx.x;  // 8192
  const int tid = threadIdx.x;
  const float* xr = x + (size_t)row * K_DIM;
  float4 v[4];
  float am = 0.0f;
#pragma unroll
  for (int i = 0; i < 4; ++i) {
    v[i] = reinterpret_cast<const float4*>(xr)[tid * 4 + i];
    am = fmaxf(am, fmaxf(fmaxf(fabsf(v[i].x), fabsf(v[i].y)),
                         fmaxf(fabsf(v[i].z), fabsf(v[i].w))));
  }
  for (int off = 32; off > 0; off >>= 1) am = fmaxf(am, __shfl_down(am, off));
  __shared__ float sm[4];
  if ((tid & 63) == 0) sm[tid >> 6] = am;
  __syncthreads();
  const float bm = fmaxf(fmaxf(fmaxf(sm[0], sm[1]), fmaxf(sm[2], sm[3])), 1e-20f);
  if (tid == 0) xs[row] = bm / 127.0f;
  const float inv = 127.0f / bm;
  union { signed char c[16]; int4 q; } u;
#pragma unroll
  for (int i = 0; i < 4; ++i) {
    u.c[i * 4 + 0] = (signed char)(int)rintf(v[i].x * inv);
    u.c[i * 4 + 1] = (signed char)(int)rintf(v[i].y * inv);
    u.c[i * 4 + 2] = (signed char)(int)rintf(v[i].z * inv);
    u.c[i * 4 + 3] = (signed char)(int)rintf(v[i].w * inv);
  }
  *reinterpret_cast<int4*>(xq + (size_t)row * K_DIM + tid * 16) = u.q;
}

// ---------- K5: 256x256 i8 MFMA GEMM, m201-phase schedule, 3 LDS buffers ----
// i8 LDS swizzle (verified R13): 64B rows = 4x16B slots; logical slot c at
// phys slot c ^ ((row>>1)&3); inverse-swizzled glds source + swizzled ds_read.
__global__ __launch_bounds__(512, 2) void k_gemm(const signed char* __restrict__ Aq,
                                                 const signed char* __restrict__ Bq,
                                                 const float* __restrict__ xs,
                                                 const float* __restrict__ bias,
                                                 float* __restrict__ C) {
  __shared__ unsigned char lds[3][2][256][64];  // 96 KiB: [buf][op A=0/B=1][row][col]

  const int tid = threadIdx.x;
  const int wid = tid >> 6;   // 0..7
  const int lane = tid & 63;
  const int wm = wid >> 2;    // 0..1
  const int wn = wid & 3;     // 0..3
  const int l15 = lane & 15;
  const int l4 = lane >> 4;   // 0..3

  // bijective XCD col-chunk swizzle: 512 blocks = 8 XCDs x 64; XCD c owns
  // bx in {2c, 2c+1} (its 2 B col-panels = 2MB stay L2-resident), all by.
  const int c8 = blockIdx.x & 7;
  const int idx = blockIdx.x >> 3;
  const int bcol = (c8 * 2 + (idx & 1)) * BN;
  const int brow = (idx >> 1) * BM;

  // staging: lane covers (row = wid*16 + lane>>2, slot = lane&3) of a 128-row half
  const int srow = wid * 16 + (lane >> 2);
  const int scol = ((lane & 3) ^ ((lane >> 3) & 3)) << 4;  // inverse-swizzled src byte
  // ds_read: phys slot = l4 ^ ((row>>1)&3); row ≡ l15 (mod 8)
  const int rdoff = ((l4 ^ ((l15 >> 1) & 3)) << 4);

#define STAGE1(buf, op, half, kt)                                                  \
  do {                                                                             \
    const signed char* g =                                                         \
        ((op) ? Bq + (size_t)(bcol + (half)*128 + srow) * K_DIM                    \
              : Aq + (size_t)(brow + (half)*128 + srow) * K_DIM) + (kt)*64 + scol; \
    load_lds16(g, (char*)&lds[buf][op][(half)*128][0] + (size_t)wid * 1024);       \
  } while (0)

#define RD_A(AR, buf, i0)                                                         \
  _Pragma("unroll") for (int i = 0; i < 4; ++i)                                   \
    AR[i] = *reinterpret_cast<const vi4*>(                                        \
        &lds[buf][0][0][0] + (size_t)(wm * 128 + ((i0) + i) * 16 + l15) * 64 + rdoff);
#define RD_B(BR, buf, p0)                                                         \
  _Pragma("unroll") for (int p = 0; p < 2; ++p)                                   \
    BR[p] = *reinterpret_cast<const vi4*>(                                        \
        &lds[buf][1][0][0] + (size_t)(((p0) + p) * 64 + wn * 16 + l15) * 64 + rdoff);

#define MFMAQ(AV, BV, IO, PO)                                                     \
  _Pragma("unroll") for (int i = 0; i < 4; ++i)                                   \
    _Pragma("unroll") for (int p = 0; p < 2; ++p)                                 \
      acc[(IO) + i][(PO) + p] = __builtin_amdgcn_mfma_i32_16x16x64_i8(            \
          AV[i], BV[p], acc[(IO) + i][(PO) + p], 0, 0, 0);

  vi4 acc[8][4];
#pragma unroll
  for (int i = 0; i < 8; ++i)
#pragma unroll
    for (int p = 0; p < 4; ++p)
#pragma unroll
      for (int e = 0; e < 4; ++e) acc[i][p][e] = 0;

  vi4 aL[4], aH[4], bL[2], bH[2];

  // prologue: tile0 -> buf0, tile1 -> buf1
  STAGE1(0, 0, 0, 0); STAGE1(0, 0, 1, 0); STAGE1(0, 1, 0, 0); STAGE1(0, 1, 1, 0);
  STAGE1(1, 0, 0, 1); STAGE1(1, 0, 1, 1); STAGE1(1, 1, 0, 1); STAGE1(1, 1, 1, 1);
  VMW4();  // tile0's 4 (oldest) landed; tile1 in flight
  BAR();

  int cur = 0;
  for (int t = 0; t < 63; ++t) {
    const int stg = (cur == 0) ? 2 : cur - 1;  // (t+2)%3
    // ---- phase 0: aL,bL reads + A-staging -> BAR -> lgkm0 -> Q0 (8 MFMA) ----
    RD_A(aL, cur, 0);
    RD_B(bL, cur, 0);
    SB0();
    if (t < 62) { STAGE1(stg, 0, 0, t + 2); STAGE1(stg, 0, 1, t + 2); }
    BAR();
    LGKM0();
    __builtin_amdgcn_s_setprio(1);
    MFMAQ(aL, bL, 0, 0);
    __builtin_amdgcn_s_setprio(0);
    BAR();
    // ---- phase 1: aH,bH reads + B-staging -> BAR -> lgkm0 -> Q1,Q2,Q3 ----
    RD_A(aH, cur, 4);
    RD_B(bH, cur, 2);
    SB0();
    if (t < 62) { STAGE1(stg, 1, 0, t + 2); STAGE1(stg, 1, 1, t + 2); }
    BAR();
    LGKM0();
    __builtin_amdgcn_s_setprio(1);
    MFMAQ(aH, bH, 4, 2);
    MFMAQ(aL, bH, 0, 2);
    MFMAQ(aH, bL, 4, 0);
    __builtin_amdgcn_s_setprio(0);
    // boundary: publish tile t+1 (4 newest outstanding = tile t+2's stages)
    if (t < 62) VMW4(); else VMW0();
    BAR();
    cur = (cur == 2) ? 0 : cur + 1;
  }

  // ---- tail tile 63 (cur = 0; staged at t=61 into buf0; already published) ----
  RD_A(aL, cur, 0); RD_B(bL, cur, 0);
  RD_A(aH, cur, 4); RD_B(bH, cur, 2);
  LGKM0();
  __builtin_amdgcn_s_setprio(1);
  MFMAQ(aL, bL, 0, 0);
  MFMAQ(aH, bH, 4, 2);
  MFMAQ(aL, bH, 0, 2);
  MFMAQ(aH, bL, 4, 0);
  __builtin_amdgcn_s_setprio(0);

  // ---- epilogue: C/D layout col=lane&15, row=(lane>>4)*4+j; dequant + bias ----
  float bi[4];
#pragma unroll
  for (int p = 0; p < 4; ++p) bi[p] = bias[bcol + p * 64 + wn * 16 + l15];
#pragma unroll
  for (int i = 0; i < 8; ++i) {
#pragma unroll
    for (int j = 0; j < 4; ++j) {
      const int row = brow + wm * 128 + i * 16 + l4 * 4 + j;
      const float sc = xs[row];
      float* crow = C + (size_t)row * N_DIM + bcol + wn * 16 + l15;
#pragma unroll
      for (int p = 0; p < 4; ++p) crow[p * 64] = (float)acc[i][p][j] * sc + bi[p];
    }
  }
#undef STAGE1
#undef RD_A
#undef RD_B
#undef MFMAQ
}

extern "C" void kernel_launch(void* const* d_in, const int* in_sizes, int n_in,
                              void* d_out, int out_size, void* d_ws, size_t ws_size,
                              hipStream_t stream) {
  (void)in_sizes; (void)n_in; (void)out_size; (void)ws_size;
  const float* x = (const float*)d_in[0];
  const float* w = (const float*)d_in[1];
  const float* bias = (const float*)d_in[2];
  float* out = (float*)d_out;

  char* ws = (char*)d_ws;
  signed char* xq = (signed char*)ws;                                   // 32 MB
  signed char* qb = (signed char*)(ws + (size_t)M_DIM * K_DIM);         // 16 MB
  float* xs = (float*)(ws + (size_t)M_DIM * K_DIM + (size_t)N_DIM * K_DIM);  // 32 KB
  double* partial = (double*)((char*)xs + M_DIM * sizeof(float));
  float* gamma = (float*)(partial + 2048);

  k_abs_partial<<<2048, 256, 0, stream>>>(w, partial);
  k_abs_final<<<1, 256, 0, stream>>>(partial, gamma);
  k_quant<<<2048, 256, 0, stream>>>(w, gamma, (int*)qb);
  k_quant_x<<<M_DIM, 256, 0, stream>>>(x, xq, xs);

  k_gemm<<<512, 512, 0, stream>>>(xq, qb, xs, bias, out);
}